// Round 1
// baseline (732.270 us; speedup 1.0000x reference)
//
#include <hip/hip_runtime.h>

// ---------------------------------------------------------------------------
// GNNML1: 5 blocks of {h1=relu(x@Wa+ba) | h2=relu(scatter_sum((x@Wv)[src]->dst)+bv)
//         | h3=relu((x@Wb+bb)*(x@Wc+bc))} concat -> pool by graph -> 2-layer MLP.
// All float32. N=50000, E=800000, G=64, NOUT=32, NIN=96.
// ---------------------------------------------------------------------------

// Computes the three linear branches + conv pre-aggregation values for a layer.
// Writes hout[:,0:32]=relu(A), hout[:,32:64]=0 (scatter target), hout[:,64:96]=relu(B*C),
// conv_pre[:,0:32] = x @ Wv (bias added post-aggregation).
// Mapping: block = 256 threads = 8 groups x 32 output-channels; each group owns 8 nodes.
template <int NIN>
__global__ void __launch_bounds__(256) lin_kernel(
    const float* __restrict__ hin,       // [N, NIN]
    float* __restrict__ hout,            // [N, 96]
    float* __restrict__ conv_pre,        // [N, 32]
    const float* __restrict__ Wa, const float* __restrict__ ba,
    const float* __restrict__ Wv,
    const float* __restrict__ Wb, const float* __restrict__ bb,
    const float* __restrict__ Wc, const float* __restrict__ bc,
    int n_nodes)
{
    __shared__ float sW[4][NIN * 32];
    __shared__ float sbias[3][32];
    __shared__ float sx[64 * NIN];

    const int tid = threadIdx.x;
    for (int i = tid; i < NIN * 32; i += 256) {
        sW[0][i] = Wa[i];
        sW[1][i] = Wv[i];
        sW[2][i] = Wb[i];
        sW[3][i] = Wc[i];
    }
    if (tid < 32) {
        sbias[0][tid] = ba[tid];
        sbias[1][tid] = bb[tid];
        sbias[2][tid] = bc[tid];
    }
    __syncthreads();

    const int group = tid >> 5;   // 0..7
    const int j     = tid & 31;   // output channel
    const int npasses = (n_nodes + 63) / 64;

    for (int pass = blockIdx.x; pass < npasses; pass += gridDim.x) {
        const int base = pass * 64;
        // stage 64 nodes' inputs (coalesced)
        for (int i = tid; i < 64 * NIN; i += 256) {
            const int node = base + i / NIN;
            sx[i] = (node < n_nodes) ? hin[(long)base * NIN + i] : 0.f;
        }
        __syncthreads();

        float aA[8], aV[8], aB[8], aC[8];
#pragma unroll
        for (int g = 0; g < 8; ++g) {
            aA[g] = sbias[0][j];
            aV[g] = 0.f;
            aB[g] = sbias[1][j];
            aC[g] = sbias[2][j];
        }
        const float* xg = &sx[group * 8 * NIN];
#pragma unroll 8
        for (int k = 0; k < NIN; ++k) {
            const float wA = sW[0][k * 32 + j];
            const float wV = sW[1][k * 32 + j];
            const float wB = sW[2][k * 32 + j];
            const float wC = sW[3][k * 32 + j];
#pragma unroll
            for (int g = 0; g < 8; ++g) {
                const float xk = xg[g * NIN + k];
                aA[g] = fmaf(xk, wA, aA[g]);
                aV[g] = fmaf(xk, wV, aV[g]);
                aB[g] = fmaf(xk, wB, aB[g]);
                aC[g] = fmaf(xk, wC, aC[g]);
            }
        }
#pragma unroll
        for (int g = 0; g < 8; ++g) {
            const int node = base + group * 8 + g;
            if (node < n_nodes) {
                float* o = hout + (long)node * 96;
                o[j]      = fmaxf(aA[g], 0.f);
                o[32 + j] = 0.f;                      // scatter target
                o[64 + j] = fmaxf(aB[g] * aC[g], 0.f);
                conv_pre[(long)node * 32 + j] = aV[g];
            }
        }
        __syncthreads();
    }
}

// One thread per (edge, channel): hout[dst, 32+c] += conv_pre[src, c]
__global__ void __launch_bounds__(256) scatter_kernel(
    const int* __restrict__ src, const int* __restrict__ dst,
    const float* __restrict__ conv_pre, float* __restrict__ hout,
    int n_edges)
{
    const int i = blockIdx.x * 256 + threadIdx.x;
    if (i >= n_edges * 32) return;
    const int e = i >> 5;
    const int c = i & 31;
    const int s = src[e];
    const int d = dst[e];
    atomicAdd(&hout[(long)d * 96 + 32 + c], conv_pre[(long)s * 32 + c]);
}

// hout[:,32:64] = relu(hout[:,32:64] + conv_b)
__global__ void __launch_bounds__(256) finalize_kernel(
    float* __restrict__ hout, const float* __restrict__ cb, int n_nodes)
{
    const int i = blockIdx.x * 256 + threadIdx.x;
    if (i >= n_nodes * 32) return;
    const int n = i >> 5;
    const int c = i & 31;
    const long idx = (long)n * 96 + 32 + c;
    hout[idx] = fmaxf(hout[idx] + cb[c], 0.f);
}

// Segment-sum pool exploiting sorted batch: each thread accumulates a run of 16
// nodes for one channel, flushing one atomic per graph-change.
__global__ void __launch_bounds__(192) pool_kernel(
    const float* __restrict__ h, const int* __restrict__ batch,
    float* __restrict__ pooled, int n_nodes)
{
    const int c    = threadIdx.x % 96;
    const int sub  = threadIdx.x / 96;
    const int chunk = blockIdx.x * 2 + sub;
    const int base  = chunk * 16;
    if (base >= n_nodes) return;
    float acc = 0.f;
    int gcur = batch[base];
    for (int i = 0; i < 16; ++i) {
        const int n = base + i;
        if (n >= n_nodes) break;
        const int g = batch[n];
        if (g != gcur) {
            atomicAdd(&pooled[gcur * 96 + c], acc);
            acc = 0.f;
            gcur = g;
        }
        acc += h[(long)n * 96 + c];
    }
    atomicAdd(&pooled[gcur * 96 + c], acc);
}

// out[g] = fc2_b + sum_j (fc1_b[j] + sum_k pooled[g,k] fc1_W[k,j]) * fc2_W[j]
__global__ void readout_kernel(
    const float* __restrict__ pooled,
    const float* __restrict__ fc1W, const float* __restrict__ fc1b,
    const float* __restrict__ fc2W, const float* __restrict__ fc2b,
    float* __restrict__ out, int n_graphs)
{
    const int g = threadIdx.x;
    if (g >= n_graphs) return;
    float acc = fc2b[0];
    for (int jj = 0; jj < 32; ++jj) {
        float s = fc1b[jj];
        for (int k = 0; k < 96; ++k)
            s = fmaf(pooled[g * 96 + k], fc1W[k * 32 + jj], s);
        acc = fmaf(s, fc2W[jj], acc);
    }
    out[g] = acc;
}

extern "C" void kernel_launch(void* const* d_in, const int* in_sizes, int n_in,
                              void* d_out, int out_size, void* d_ws, size_t ws_size,
                              hipStream_t stream)
{
    const float* x        = (const float*)d_in[0];
    const int*   edge_idx = (const int*)d_in[1];
    const int*   batch    = (const int*)d_in[2];
    const float* conv1_W  = (const float*)d_in[3];
    const float* conv1_b  = (const float*)d_in[4];
    const float* fc11_W   = (const float*)d_in[5];
    const float* fc11_b   = (const float*)d_in[6];
    const float* fc12_W   = (const float*)d_in[7];
    const float* fc12_b   = (const float*)d_in[8];
    const float* fc13_W   = (const float*)d_in[9];
    const float* fc13_b   = (const float*)d_in[10];
    const float* conv_W   = (const float*)d_in[11];
    const float* conv_b   = (const float*)d_in[12];
    const float* fcA_W    = (const float*)d_in[13];
    const float* fcA_b    = (const float*)d_in[14];
    const float* fcB_W    = (const float*)d_in[15];
    const float* fcB_b    = (const float*)d_in[16];
    const float* fcC_W    = (const float*)d_in[17];
    const float* fcC_b    = (const float*)d_in[18];
    const float* fc1_W    = (const float*)d_in[19];
    const float* fc1_b    = (const float*)d_in[20];
    const float* fc2_W    = (const float*)d_in[21];
    const float* fc2_b    = (const float*)d_in[22];

    const int n_nodes = in_sizes[2];       // 50000
    const int n_edges = in_sizes[1] / 2;   // 800000
    const int n_graphs = out_size;         // 64
    const int* src = edge_idx;
    const int* dst = edge_idx + n_edges;

    // workspace layout (floats)
    float* hA       = (float*)d_ws;
    float* hB       = hA + (size_t)n_nodes * 96;
    float* conv_pre = hB + (size_t)n_nodes * 96;
    float* pooled   = conv_pre + (size_t)n_nodes * 32;
    (void)ws_size;

    hipMemsetAsync(pooled, 0, (size_t)n_graphs * 96 * sizeof(float), stream);

    const int scat_blocks = (n_edges * 32 + 255) / 256;
    const int fin_blocks  = (n_nodes * 32 + 255) / 256;

    // ---- layer 1 (NIN=2) ----
    lin_kernel<2><<<512, 256, 0, stream>>>(
        x, hA, conv_pre,
        fc11_W, fc11_b, conv1_W, fc12_W, fc12_b, fc13_W, fc13_b, n_nodes);
    scatter_kernel<<<scat_blocks, 256, 0, stream>>>(src, dst, conv_pre, hA, n_edges);
    finalize_kernel<<<fin_blocks, 256, 0, stream>>>(hA, conv1_b, n_nodes);

    // ---- layers 2..5 (NIN=96) ----
    float* cur = hA;
    float* nxt = hB;
    for (int i = 0; i < 4; ++i) {
        lin_kernel<96><<<512, 256, 0, stream>>>(
            cur, nxt, conv_pre,
            fcA_W + i * 3072, fcA_b + i * 32,
            conv_W + i * 3072,
            fcB_W + i * 3072, fcB_b + i * 32,
            fcC_W + i * 3072, fcC_b + i * 32, n_nodes);
        scatter_kernel<<<scat_blocks, 256, 0, stream>>>(src, dst, conv_pre, nxt, n_edges);
        finalize_kernel<<<fin_blocks, 256, 0, stream>>>(nxt, conv_b + i * 32, n_nodes);
        float* t = cur; cur = nxt; nxt = t;
    }

    // ---- pool + readout ----
    {
        const int chunks = (n_nodes + 15) / 16;
        const int blocks = (chunks + 1) / 2;
        pool_kernel<<<blocks, 192, 0, stream>>>(cur, batch, pooled, n_nodes);
    }
    readout_kernel<<<1, 64, 0, stream>>>(pooled, fc1_W, fc1_b, fc2_W, fc2_b,
                                         (float*)d_out, n_graphs);
}

// Round 2
// 548.876 us; speedup vs baseline: 1.3341x; 1.3341x over previous
//
#include <hip/hip_runtime.h>

// ---------------------------------------------------------------------------
// GNNML1: 5 blocks of {h1=relu(x@Wa+ba) | h2=relu(sum_{e:dst=n}(x@Wv)[src]+bv)
//         | h3=relu((x@Wb+bb)*(x@Wc+cb))} concat -> pool by graph -> MLP.
// R1: atomic scatter replaced by CSR build (once) + atomic-free gather.
// ---------------------------------------------------------------------------

template <int NIN>
__global__ void __launch_bounds__(256) lin_kernel(
    const float* __restrict__ hin,       // [N, NIN]
    float* __restrict__ hout,            // [N, 96]
    float* __restrict__ conv_pre,        // [N, 32]
    const float* __restrict__ Wa, const float* __restrict__ ba,
    const float* __restrict__ Wv,
    const float* __restrict__ Wb, const float* __restrict__ bb,
    const float* __restrict__ Wc, const float* __restrict__ bc,
    int n_nodes)
{
    __shared__ float sW[4][NIN * 32];
    __shared__ float sbias[3][32];
    __shared__ float sx[64 * NIN];

    const int tid = threadIdx.x;
    for (int i = tid; i < NIN * 32; i += 256) {
        sW[0][i] = Wa[i];
        sW[1][i] = Wv[i];
        sW[2][i] = Wb[i];
        sW[3][i] = Wc[i];
    }
    if (tid < 32) {
        sbias[0][tid] = ba[tid];
        sbias[1][tid] = bb[tid];
        sbias[2][tid] = bc[tid];
    }
    __syncthreads();

    const int group = tid >> 5;   // 0..7
    const int j     = tid & 31;   // output channel
    const int npasses = (n_nodes + 63) / 64;

    for (int pass = blockIdx.x; pass < npasses; pass += gridDim.x) {
        const int base = pass * 64;
        for (int i = tid; i < 64 * NIN; i += 256) {
            const int node = base + i / NIN;
            sx[i] = (node < n_nodes) ? hin[(long)base * NIN + i] : 0.f;
        }
        __syncthreads();

        float aA[8], aV[8], aB[8], aC[8];
#pragma unroll
        for (int g = 0; g < 8; ++g) {
            aA[g] = sbias[0][j];
            aV[g] = 0.f;
            aB[g] = sbias[1][j];
            aC[g] = sbias[2][j];
        }
        const float* xg = &sx[group * 8 * NIN];
#pragma unroll 8
        for (int k = 0; k < NIN; ++k) {
            const float wA = sW[0][k * 32 + j];
            const float wV = sW[1][k * 32 + j];
            const float wB = sW[2][k * 32 + j];
            const float wC = sW[3][k * 32 + j];
#pragma unroll
            for (int g = 0; g < 8; ++g) {
                const float xk = xg[g * NIN + k];
                aA[g] = fmaf(xk, wA, aA[g]);
                aV[g] = fmaf(xk, wV, aV[g]);
                aB[g] = fmaf(xk, wB, aB[g]);
                aC[g] = fmaf(xk, wC, aC[g]);
            }
        }
#pragma unroll
        for (int g = 0; g < 8; ++g) {
            const int node = base + group * 8 + g;
            if (node < n_nodes) {
                float* o = hout + (long)node * 96;
                o[j]      = fmaxf(aA[g], 0.f);
                o[64 + j] = fmaxf(aB[g] * aC[g], 0.f);
                conv_pre[(long)node * 32 + j] = aV[g];
            }
        }
        __syncthreads();
    }
}

// ---- CSR build (once per call) ----
__global__ void __launch_bounds__(256) count_kernel(
    const int* __restrict__ dst, int* __restrict__ deg, int n_edges)
{
    const int e = blockIdx.x * 256 + threadIdx.x;
    if (e < n_edges) atomicAdd(&deg[dst[e]], 1);
}

__global__ void __launch_bounds__(1024) scan_kernel(
    const int* __restrict__ deg, int* __restrict__ row_start, int n_nodes)
{
    __shared__ int part[1024];
    const int tid = threadIdx.x;
    const int chunk = (n_nodes + 1023) / 1024;
    const int beg = tid * chunk;
    const int end = min(beg + chunk, n_nodes);
    int s = 0;
    for (int i = beg; i < end; ++i) s += deg[i];
    part[tid] = s;
    __syncthreads();
    for (int off = 1; off < 1024; off <<= 1) {
        int v = (tid >= off) ? part[tid - off] : 0;
        __syncthreads();
        part[tid] += v;
        __syncthreads();
    }
    int run = (tid == 0) ? 0 : part[tid - 1];
    for (int i = beg; i < end; ++i) {
        row_start[i] = run;
        run += deg[i];
    }
    if (tid == 1023) row_start[n_nodes] = part[1023];
}

__global__ void __launch_bounds__(256) fill_kernel(
    const int* __restrict__ src, const int* __restrict__ dst,
    const int* __restrict__ row_start, int* __restrict__ cursor,
    int* __restrict__ csr_src, int n_edges)
{
    const int e = blockIdx.x * 256 + threadIdx.x;
    if (e >= n_edges) return;
    const int d = dst[e];
    const int pos = atomicAdd(&cursor[d], 1);
    csr_src[row_start[d] + pos] = src[e];
}

// ---- per-layer aggregation: hout[n,32+c] = relu(sum_incident conv_pre[src,c] + cb[c])
__global__ void __launch_bounds__(256) gather_kernel(
    const int* __restrict__ row_start, const int* __restrict__ csr_src,
    const float* __restrict__ conv_pre, const float* __restrict__ cb,
    float* __restrict__ hout, int n_nodes)
{
    const int t = blockIdx.x * 256 + threadIdx.x;
    const int n = t >> 5;
    const int c = t & 31;
    if (n >= n_nodes) return;
    const int beg = row_start[n];
    const int end = row_start[n + 1];
    float acc = 0.f;
    int i = beg;
    for (; i + 1 < end; i += 2) {
        const int s0 = csr_src[i];
        const int s1 = csr_src[i + 1];
        acc += conv_pre[(long)s0 * 32 + c];
        acc += conv_pre[(long)s1 * 32 + c];
    }
    if (i < end) acc += conv_pre[(long)csr_src[i] * 32 + c];
    hout[(long)n * 96 + 32 + c] = fmaxf(acc + cb[c], 0.f);
}

// ---- pool + readout ----
__global__ void __launch_bounds__(192) pool_kernel(
    const float* __restrict__ h, const int* __restrict__ batch,
    float* __restrict__ pooled, int n_nodes)
{
    const int c    = threadIdx.x % 96;
    const int sub  = threadIdx.x / 96;
    const int chunk = blockIdx.x * 2 + sub;
    const int base  = chunk * 16;
    if (base >= n_nodes) return;
    float acc = 0.f;
    int gcur = batch[base];
    for (int i = 0; i < 16; ++i) {
        const int n = base + i;
        if (n >= n_nodes) break;
        const int g = batch[n];
        if (g != gcur) {
            atomicAdd(&pooled[gcur * 96 + c], acc);
            acc = 0.f;
            gcur = g;
        }
        acc += h[(long)n * 96 + c];
    }
    atomicAdd(&pooled[gcur * 96 + c], acc);
}

__global__ void readout_kernel(
    const float* __restrict__ pooled,
    const float* __restrict__ fc1W, const float* __restrict__ fc1b,
    const float* __restrict__ fc2W, const float* __restrict__ fc2b,
    float* __restrict__ out, int n_graphs)
{
    const int g = threadIdx.x;
    if (g >= n_graphs) return;
    float acc = fc2b[0];
    for (int jj = 0; jj < 32; ++jj) {
        float s = fc1b[jj];
        for (int k = 0; k < 96; ++k)
            s = fmaf(pooled[g * 96 + k], fc1W[k * 32 + jj], s);
        acc = fmaf(s, fc2W[jj], acc);
    }
    out[g] = acc;
}

extern "C" void kernel_launch(void* const* d_in, const int* in_sizes, int n_in,
                              void* d_out, int out_size, void* d_ws, size_t ws_size,
                              hipStream_t stream)
{
    const float* x        = (const float*)d_in[0];
    const int*   edge_idx = (const int*)d_in[1];
    const int*   batch    = (const int*)d_in[2];
    const float* conv1_W  = (const float*)d_in[3];
    const float* conv1_b  = (const float*)d_in[4];
    const float* fc11_W   = (const float*)d_in[5];
    const float* fc11_b   = (const float*)d_in[6];
    const float* fc12_W   = (const float*)d_in[7];
    const float* fc12_b   = (const float*)d_in[8];
    const float* fc13_W   = (const float*)d_in[9];
    const float* fc13_b   = (const float*)d_in[10];
    const float* conv_W   = (const float*)d_in[11];
    const float* conv_b   = (const float*)d_in[12];
    const float* fcA_W    = (const float*)d_in[13];
    const float* fcA_b    = (const float*)d_in[14];
    const float* fcB_W    = (const float*)d_in[15];
    const float* fcB_b    = (const float*)d_in[16];
    const float* fcC_W    = (const float*)d_in[17];
    const float* fcC_b    = (const float*)d_in[18];
    const float* fc1_W    = (const float*)d_in[19];
    const float* fc1_b    = (const float*)d_in[20];
    const float* fc2_W    = (const float*)d_in[21];
    const float* fc2_b    = (const float*)d_in[22];

    const int n_nodes  = in_sizes[2];       // 50000
    const int n_edges  = in_sizes[1] / 2;   // 800000
    const int n_graphs = out_size;          // 64
    const int* src = edge_idx;
    const int* dst = edge_idx + n_edges;

    // workspace layout
    float* hA        = (float*)d_ws;
    float* hB        = hA + (size_t)n_nodes * 96;
    float* conv_pre  = hB + (size_t)n_nodes * 96;
    float* pooled    = conv_pre + (size_t)n_nodes * 32;
    int*   deg       = (int*)(pooled + (size_t)n_graphs * 96);
    int*   row_start = deg + n_nodes;          // n_nodes+1
    int*   cursor    = row_start + n_nodes + 1;
    int*   csr_src   = cursor + n_nodes;
    (void)ws_size;

    hipMemsetAsync(pooled, 0, (size_t)n_graphs * 96 * sizeof(float), stream);
    hipMemsetAsync(deg, 0, (size_t)n_nodes * sizeof(int), stream);
    hipMemsetAsync(cursor, 0, (size_t)n_nodes * sizeof(int), stream);

    const int eblocks = (n_edges + 255) / 256;
    const int gblocks = (n_nodes * 32 + 255) / 256;

    // ---- CSR build (amortized over 5 layers) ----
    count_kernel<<<eblocks, 256, 0, stream>>>(dst, deg, n_edges);
    scan_kernel<<<1, 1024, 0, stream>>>(deg, row_start, n_nodes);
    fill_kernel<<<eblocks, 256, 0, stream>>>(src, dst, row_start, cursor, csr_src, n_edges);

    // ---- layer 1 (NIN=2) ----
    lin_kernel<2><<<512, 256, 0, stream>>>(
        x, hA, conv_pre,
        fc11_W, fc11_b, conv1_W, fc12_W, fc12_b, fc13_W, fc13_b, n_nodes);
    gather_kernel<<<gblocks, 256, 0, stream>>>(row_start, csr_src, conv_pre, conv1_b, hA, n_nodes);

    // ---- layers 2..5 (NIN=96) ----
    float* cur = hA;
    float* nxt = hB;
    for (int i = 0; i < 4; ++i) {
        lin_kernel<96><<<512, 256, 0, stream>>>(
            cur, nxt, conv_pre,
            fcA_W + i * 3072, fcA_b + i * 32,
            conv_W + i * 3072,
            fcB_W + i * 3072, fcB_b + i * 32,
            fcC_W + i * 3072, fcC_b + i * 32, n_nodes);
        gather_kernel<<<gblocks, 256, 0, stream>>>(row_start, csr_src, conv_pre,
                                                   conv_b + i * 32, nxt, n_nodes);
        float* t = cur; cur = nxt; nxt = t;
    }

    // ---- pool + readout ----
    {
        const int chunks = (n_nodes + 15) / 16;
        const int blocks = (chunks + 1) / 2;
        pool_kernel<<<blocks, 192, 0, stream>>>(cur, batch, pooled, n_nodes);
    }
    readout_kernel<<<1, 64, 0, stream>>>(pooled, fc1_W, fc1_b, fc2_W, fc2_b,
                                         (float*)d_out, n_graphs);
}

// Round 3
// 476.711 us; speedup vs baseline: 1.5361x; 1.1514x over previous
//
#include <hip/hip_runtime.h>

// ---------------------------------------------------------------------------
// GNNML1: 5 blocks of {h1=relu(x@Wa+ba) | h2=relu(sum_{e:dst=n}(x@Wv)[src]+bv)
//         | h3=relu((x@Wb+bb)*(x@Wc+cb))} concat -> pool by graph -> MLP.
// R1: atomic scatter -> CSR build + atomic-free gather.
// R2: single-block scan (76us) -> 3-stage hierarchical scan (<10us).
// ---------------------------------------------------------------------------

template <int NIN>
__global__ void __launch_bounds__(256) lin_kernel(
    const float* __restrict__ hin,       // [N, NIN]
    float* __restrict__ hout,            // [N, 96]
    float* __restrict__ conv_pre,        // [N, 32]
    const float* __restrict__ Wa, const float* __restrict__ ba,
    const float* __restrict__ Wv,
    const float* __restrict__ Wb, const float* __restrict__ bb,
    const float* __restrict__ Wc, const float* __restrict__ bc,
    int n_nodes)
{
    __shared__ float sW[4][NIN * 32];
    __shared__ float sbias[3][32];
    __shared__ float sx[64 * NIN];

    const int tid = threadIdx.x;
    for (int i = tid; i < NIN * 32; i += 256) {
        sW[0][i] = Wa[i];
        sW[1][i] = Wv[i];
        sW[2][i] = Wb[i];
        sW[3][i] = Wc[i];
    }
    if (tid < 32) {
        sbias[0][tid] = ba[tid];
        sbias[1][tid] = bb[tid];
        sbias[2][tid] = bc[tid];
    }
    __syncthreads();

    const int group = tid >> 5;   // 0..7
    const int j     = tid & 31;   // output channel
    const int npasses = (n_nodes + 63) / 64;

    for (int pass = blockIdx.x; pass < npasses; pass += gridDim.x) {
        const int base = pass * 64;
        for (int i = tid; i < 64 * NIN; i += 256) {
            const int node = base + i / NIN;
            sx[i] = (node < n_nodes) ? hin[(long)base * NIN + i] : 0.f;
        }
        __syncthreads();

        float aA[8], aV[8], aB[8], aC[8];
#pragma unroll
        for (int g = 0; g < 8; ++g) {
            aA[g] = sbias[0][j];
            aV[g] = 0.f;
            aB[g] = sbias[1][j];
            aC[g] = sbias[2][j];
        }
        const float* xg = &sx[group * 8 * NIN];
#pragma unroll 8
        for (int k = 0; k < NIN; ++k) {
            const float wA = sW[0][k * 32 + j];
            const float wV = sW[1][k * 32 + j];
            const float wB = sW[2][k * 32 + j];
            const float wC = sW[3][k * 32 + j];
#pragma unroll
            for (int g = 0; g < 8; ++g) {
                const float xk = xg[g * NIN + k];
                aA[g] = fmaf(xk, wA, aA[g]);
                aV[g] = fmaf(xk, wV, aV[g]);
                aB[g] = fmaf(xk, wB, aB[g]);
                aC[g] = fmaf(xk, wC, aC[g]);
            }
        }
#pragma unroll
        for (int g = 0; g < 8; ++g) {
            const int node = base + group * 8 + g;
            if (node < n_nodes) {
                float* o = hout + (long)node * 96;
                o[j]      = fmaxf(aA[g], 0.f);
                o[64 + j] = fmaxf(aB[g] * aC[g], 0.f);
                conv_pre[(long)node * 32 + j] = aV[g];
            }
        }
        __syncthreads();
    }
}

// ---- CSR build (once per call) ----
__global__ void __launch_bounds__(256) count_kernel(
    const int* __restrict__ dst, int* __restrict__ deg, int n_edges)
{
    const int e = blockIdx.x * 256 + threadIdx.x;
    if (e < n_edges) atomicAdd(&deg[dst[e]], 1);
}

// Stage 1: per-block sums of deg (256 elements per block).
__global__ void __launch_bounds__(256) scan_partial_kernel(
    const int* __restrict__ deg, int* __restrict__ block_sums, int n_nodes)
{
    __shared__ int red[256];
    const int tid = threadIdx.x;
    const int i = blockIdx.x * 256 + tid;
    red[tid] = (i < n_nodes) ? deg[i] : 0;
    __syncthreads();
    for (int off = 128; off > 0; off >>= 1) {
        if (tid < off) red[tid] += red[tid + off];
        __syncthreads();
    }
    if (tid == 0) block_sums[blockIdx.x] = red[0];
}

// Stage 2: single small block turns block_sums into exclusive block offsets.
// Requires nblocks <= 256.
__global__ void __launch_bounds__(256) scan_sums_kernel(
    int* __restrict__ block_sums, int nblocks)
{
    __shared__ int s[256];
    const int tid = threadIdx.x;
    const int v = (tid < nblocks) ? block_sums[tid] : 0;
    s[tid] = v;
    __syncthreads();
    for (int off = 1; off < 256; off <<= 1) {
        const int t = (tid >= off) ? s[tid - off] : 0;
        __syncthreads();
        s[tid] += t;
        __syncthreads();
    }
    if (tid < nblocks) block_sums[tid] = s[tid] - v;   // exclusive
}

// Stage 3: per-block local exclusive scan + block offset -> row_start.
__global__ void __launch_bounds__(256) scan_final_kernel(
    const int* __restrict__ deg, const int* __restrict__ block_offs,
    int* __restrict__ row_start, int n_nodes)
{
    __shared__ int s[256];
    const int tid = threadIdx.x;
    const int i = blockIdx.x * 256 + tid;
    const int v = (i < n_nodes) ? deg[i] : 0;
    s[tid] = v;
    __syncthreads();
    for (int off = 1; off < 256; off <<= 1) {
        const int t = (tid >= off) ? s[tid - off] : 0;
        __syncthreads();
        s[tid] += t;
        __syncthreads();
    }
    const int excl = s[tid] - v + block_offs[blockIdx.x];
    if (i < n_nodes) row_start[i] = excl;
    if (i == n_nodes - 1) row_start[n_nodes] = excl + v;  // total
}

__global__ void __launch_bounds__(256) fill_kernel(
    const int* __restrict__ src, const int* __restrict__ dst,
    const int* __restrict__ row_start, int* __restrict__ cursor,
    int* __restrict__ csr_src, int n_edges)
{
    const int e = blockIdx.x * 256 + threadIdx.x;
    if (e >= n_edges) return;
    const int d = dst[e];
    const int pos = atomicAdd(&cursor[d], 1);
    csr_src[row_start[d] + pos] = src[e];
}

// ---- per-layer aggregation: hout[n,32+c] = relu(sum_incident conv_pre[src,c] + cb[c])
__global__ void __launch_bounds__(256) gather_kernel(
    const int* __restrict__ row_start, const int* __restrict__ csr_src,
    const float* __restrict__ conv_pre, const float* __restrict__ cb,
    float* __restrict__ hout, int n_nodes)
{
    const int t = blockIdx.x * 256 + threadIdx.x;
    const int n = t >> 5;
    const int c = t & 31;
    if (n >= n_nodes) return;
    const int beg = row_start[n];
    const int end = row_start[n + 1];
    float acc = 0.f;
    int i = beg;
    for (; i + 1 < end; i += 2) {
        const int s0 = csr_src[i];
        const int s1 = csr_src[i + 1];
        acc += conv_pre[(long)s0 * 32 + c];
        acc += conv_pre[(long)s1 * 32 + c];
    }
    if (i < end) acc += conv_pre[(long)csr_src[i] * 32 + c];
    hout[(long)n * 96 + 32 + c] = fmaxf(acc + cb[c], 0.f);
}

// ---- pool + readout ----
__global__ void __launch_bounds__(192) pool_kernel(
    const float* __restrict__ h, const int* __restrict__ batch,
    float* __restrict__ pooled, int n_nodes)
{
    const int c    = threadIdx.x % 96;
    const int sub  = threadIdx.x / 96;
    const int chunk = blockIdx.x * 2 + sub;
    const int base  = chunk * 16;
    if (base >= n_nodes) return;
    float acc = 0.f;
    int gcur = batch[base];
    for (int i = 0; i < 16; ++i) {
        const int n = base + i;
        if (n >= n_nodes) break;
        const int g = batch[n];
        if (g != gcur) {
            atomicAdd(&pooled[gcur * 96 + c], acc);
            acc = 0.f;
            gcur = g;
        }
        acc += h[(long)n * 96 + c];
    }
    atomicAdd(&pooled[gcur * 96 + c], acc);
}

__global__ void readout_kernel(
    const float* __restrict__ pooled,
    const float* __restrict__ fc1W, const float* __restrict__ fc1b,
    const float* __restrict__ fc2W, const float* __restrict__ fc2b,
    float* __restrict__ out, int n_graphs)
{
    const int g = threadIdx.x;
    if (g >= n_graphs) return;
    float acc = fc2b[0];
    for (int jj = 0; jj < 32; ++jj) {
        float s = fc1b[jj];
        for (int k = 0; k < 96; ++k)
            s = fmaf(pooled[g * 96 + k], fc1W[k * 32 + jj], s);
        acc = fmaf(s, fc2W[jj], acc);
    }
    out[g] = acc;
}

extern "C" void kernel_launch(void* const* d_in, const int* in_sizes, int n_in,
                              void* d_out, int out_size, void* d_ws, size_t ws_size,
                              hipStream_t stream)
{
    const float* x        = (const float*)d_in[0];
    const int*   edge_idx = (const int*)d_in[1];
    const int*   batch    = (const int*)d_in[2];
    const float* conv1_W  = (const float*)d_in[3];
    const float* conv1_b  = (const float*)d_in[4];
    const float* fc11_W   = (const float*)d_in[5];
    const float* fc11_b   = (const float*)d_in[6];
    const float* fc12_W   = (const float*)d_in[7];
    const float* fc12_b   = (const float*)d_in[8];
    const float* fc13_W   = (const float*)d_in[9];
    const float* fc13_b   = (const float*)d_in[10];
    const float* conv_W   = (const float*)d_in[11];
    const float* conv_b   = (const float*)d_in[12];
    const float* fcA_W    = (const float*)d_in[13];
    const float* fcA_b    = (const float*)d_in[14];
    const float* fcB_W    = (const float*)d_in[15];
    const float* fcB_b    = (const float*)d_in[16];
    const float* fcC_W    = (const float*)d_in[17];
    const float* fcC_b    = (const float*)d_in[18];
    const float* fc1_W    = (const float*)d_in[19];
    const float* fc1_b    = (const float*)d_in[20];
    const float* fc2_W    = (const float*)d_in[21];
    const float* fc2_b    = (const float*)d_in[22];

    const int n_nodes  = in_sizes[2];       // 50000
    const int n_edges  = in_sizes[1] / 2;   // 800000
    const int n_graphs = out_size;          // 64
    const int* src = edge_idx;
    const int* dst = edge_idx + n_edges;

    const int sblocks = (n_nodes + 255) / 256;     // scan blocks (196 <= 256)

    // workspace layout (deg and cursor adjacent -> one memset)
    float* hA         = (float*)d_ws;
    float* hB         = hA + (size_t)n_nodes * 96;
    float* conv_pre   = hB + (size_t)n_nodes * 96;
    float* pooled     = conv_pre + (size_t)n_nodes * 32;
    int*   deg        = (int*)(pooled + (size_t)n_graphs * 96);
    int*   cursor     = deg + n_nodes;
    int*   row_start  = cursor + n_nodes;          // n_nodes+1
    int*   block_sums = row_start + n_nodes + 1;   // sblocks
    int*   csr_src    = block_sums + sblocks;
    (void)ws_size;

    hipMemsetAsync(pooled, 0, (size_t)n_graphs * 96 * sizeof(float), stream);
    hipMemsetAsync(deg, 0, (size_t)2 * n_nodes * sizeof(int), stream);  // deg + cursor

    const int eblocks = (n_edges + 255) / 256;
    const int gblocks = (n_nodes * 32 + 255) / 256;

    // ---- CSR build ----
    count_kernel<<<eblocks, 256, 0, stream>>>(dst, deg, n_edges);
    scan_partial_kernel<<<sblocks, 256, 0, stream>>>(deg, block_sums, n_nodes);
    scan_sums_kernel<<<1, 256, 0, stream>>>(block_sums, sblocks);
    scan_final_kernel<<<sblocks, 256, 0, stream>>>(deg, block_sums, row_start, n_nodes);
    fill_kernel<<<eblocks, 256, 0, stream>>>(src, dst, row_start, cursor, csr_src, n_edges);

    // ---- layer 1 (NIN=2) ----
    lin_kernel<2><<<512, 256, 0, stream>>>(
        x, hA, conv_pre,
        fc11_W, fc11_b, conv1_W, fc12_W, fc12_b, fc13_W, fc13_b, n_nodes);
    gather_kernel<<<gblocks, 256, 0, stream>>>(row_start, csr_src, conv_pre, conv1_b, hA, n_nodes);

    // ---- layers 2..5 (NIN=96) ----
    float* cur = hA;
    float* nxt = hB;
    for (int i = 0; i < 4; ++i) {
        lin_kernel<96><<<512, 256, 0, stream>>>(
            cur, nxt, conv_pre,
            fcA_W + i * 3072, fcA_b + i * 32,
            conv_W + i * 3072,
            fcB_W + i * 3072, fcB_b + i * 32,
            fcC_W + i * 3072, fcC_b + i * 32, n_nodes);
        gather_kernel<<<gblocks, 256, 0, stream>>>(row_start, csr_src, conv_pre,
                                                   conv_b + i * 32, nxt, n_nodes);
        float* t = cur; cur = nxt; nxt = t;
    }

    // ---- pool + readout ----
    {
        const int chunks = (n_nodes + 15) / 16;
        const int blocks = (chunks + 1) / 2;
        pool_kernel<<<blocks, 192, 0, stream>>>(cur, batch, pooled, n_nodes);
    }
    readout_kernel<<<1, 64, 0, stream>>>(pooled, fc1_W, fc1_b, fc2_W, fc2_b,
                                         (float*)d_out, n_graphs);
}